// Round 4
// baseline (396.978 us; speedup 1.0000x reference)
//
#include <hip/hip_runtime.h>

// PolyPoolerTextLenSensitive — MI355X (gfx950)
//
// R3: store-path vectorization + occupancy.
//  - R2 post-mortem: LDS staging bought only ~10%, same as pure ILP. Both
//    versions shared scalar dword output stores (201 MB @ ~1.6 TB/s eff.)
//    and low block residency (41 KB LDS -> 3 blocks/CU). This round makes
//    the store stream look exactly like the 6.4 TB/s fill kernel:
//    each thread computes 4 consecutive positions of one channel and emits
//    one dwordx4 plain store (wave = 1 KB contiguous).
//  - Exact-stride patches (no pow2 padding): PMAX=1280 floats, LDS 20.6 KB
//    -> 7 blocks/CU for barrier-latency overlap.
//  - Fallback (oversized patch, not expected) shares geometry: PWe=W,
//    px0=py0=0 makes the tap offsets global.

#define NBOX 256
#define NCH  256
#define HP   8
#define CCHUNK 32
#define NSTG 4
#define PMAX 1280              // floats per staged channel patch (exact stride)
#define OUT0_ELEMS ((size_t)NBOX * NCH * HP * 32)

typedef float f32x4 __attribute__((ext_vector_type(4)));

// Bilinear geometry for one grid position: tap offsets (patch- or global-
// space depending on pxo/pyo/PWe) + mask-folded weights.
__device__ __forceinline__ void make_geo(
    const float* __restrict__ pts, int pos, int lwp, int W, int H,
    int pxo, int pyo, int PWe,
    int& o00, int& o10, int& o01, int& o11,
    float& w00, float& w10, float& w01, float& w11)
{
    const int wp = 1 << lwp;
    const int i  = pos >> lwp;
    const int j  = pos & (wp - 1);

    // boundary interp parameter (n-1 = 6 segments)
    float u  = ((j + 0.5f) / (float)wp) * 6.0f;
    int   i0 = (int)floorf(u);
    i0 = min(max(i0, 0), 5);
    float f = u - (float)i0;

    // top points: polys[b, i0], polys[b, i0+1] normalized by (1344, 800)
    float txa = pts[2 * i0]     / 1344.0f, tya = pts[2 * i0 + 1] / 800.0f;
    float txb = pts[2 * i0 + 2] / 1344.0f, tyb = pts[2 * i0 + 3] / 800.0f;
    // bottom points (reversed): pn[7+m] = polys[b, 13-m]
    int ka = 13 - i0, kb = 12 - i0;
    float bxa = pts[2 * ka] / 1344.0f, bya = pts[2 * ka + 1] / 800.0f;
    float bxb = pts[2 * kb] / 1344.0f, byb = pts[2 * kb + 1] / 800.0f;

    float topx = txa * (1.0f - f) + txb * f;
    float topy = tya * (1.0f - f) + tyb * f;
    float botx = bxa * (1.0f - f) + bxb * f;
    float boty = bya * (1.0f - f) + byb * f;

    float v  = (i + 0.5f) / 8.0f;
    float gx = topx * (1.0f - v) + botx * v;
    float gy = topy * (1.0f - v) + boty * v;

    float x = gx * (float)W - 0.5f;
    float y = gy * (float)H - 0.5f;
    float x0f = floorf(x), y0f = floorf(y);
    float fx = x - x0f,   fy = y - y0f;
    int x0 = (int)x0f, y0 = (int)y0f;
    int x1 = x0 + 1,   y1 = y0 + 1;

    int x0c = min(max(x0, 0), W - 1), x1c = min(max(x1, 0), W - 1);
    int y0c = min(max(y0, 0), H - 1), y1c = min(max(y1, 0), H - 1);
    float m00 = (x0 >= 0 && x0 < W && y0 >= 0 && y0 < H) ? 1.0f : 0.0f;
    float m10 = (x1 >= 0 && x1 < W && y0 >= 0 && y0 < H) ? 1.0f : 0.0f;
    float m01 = (x0 >= 0 && x0 < W && y1 >= 0 && y1 < H) ? 1.0f : 0.0f;
    float m11 = (x1 >= 0 && x1 < W && y1 >= 0 && y1 < H) ? 1.0f : 0.0f;

    o00 = (y0c - pyo) * PWe + (x0c - pxo);
    o10 = (y0c - pyo) * PWe + (x1c - pxo);
    o01 = (y1c - pyo) * PWe + (x0c - pxo);
    o11 = (y1c - pyo) * PWe + (x1c - pxo);
    w00 = (1.0f - fx) * (1.0f - fy) * m00;
    w10 = fx * (1.0f - fy) * m10;
    w01 = (1.0f - fx) * fy * m01;
    w11 = fx * fy * m11;
}

__global__ __launch_bounds__(256) void poly_pool_kernel(
    const float* __restrict__ f0, const float* __restrict__ f1,
    const float* __restrict__ f2, const float* __restrict__ f3,
    const float* __restrict__ polys, const int* __restrict__ img_ids,
    const int* __restrict__ lens, float* __restrict__ out)
{
    const int b    = blockIdx.y;
    const int pidk = blockIdx.z;            // 0 -> (8,32), 1 -> (8,64)
    const int lwp  = 5 + pidk;
    const int npos = HP << lwp;             // 256 or 512
    const int c0   = blockIdx.x * CCHUNK;
    const int tid  = threadIdx.x;

    float* outb = out + (pidk ? OUT0_ELEMS : (size_t)0) + (size_t)b * NCH * npos;

    // pooler routing: pooler_id = (lens > 8)
    const int pooler = (lens[b] > 8) ? 1 : 0;
    if (pooler != pidk) {
        // this box contributes zeros to this output tensor — 16B stores
        f32x4 z = (f32x4)(0.0f);
        f32x4* p = reinterpret_cast<f32x4*>(outb + (size_t)c0 * npos);
        const int total4 = (CCHUNK * npos) >> 2;   // 2048 or 4096
        for (int k = tid; k < total4; k += 256) p[k] = z;
        return;
    }

    __shared__ float pts[28];               // polys[b] : 14 points x 2
    __shared__ float patch[NSTG][PMAX];     // 20.5 KB staging
    if (tid < 28) pts[tid] = polys[b * 28 + tid];
    __syncthreads();

    // ---- level selection: s = sqrt(dx*dy) over raw points ----
    float minx = pts[0], maxx = pts[0], miny = pts[1], maxy = pts[1];
#pragma unroll
    for (int k = 1; k < 14; ++k) {
        float x = pts[2 * k], y = pts[2 * k + 1];
        minx = fminf(minx, x); maxx = fmaxf(maxx, x);
        miny = fminf(miny, y); maxy = fmaxf(maxy, y);
    }
    float s = sqrtf((maxx - minx) * (maxy - miny));
    int lvl = (int)floorf(4.0f + log2f(s / 224.0f + 1e-6f));
    lvl = min(max(lvl, 2), 5) - 2;

    const float* feat; int H, W;
    switch (lvl) {
        case 0:  feat = f0; H = 200; W = 336; break;
        case 1:  feat = f1; H = 100; W = 168; break;
        case 2:  feat = f2; H = 50;  W = 84;  break;
        default: feat = f3; H = 25;  W = 42;  break;
    }
    const int img = img_ids[b];
    const int HW  = H * W;
    const float* featimg = feat + (size_t)img * NCH * HW;

    // ---- patch bounding box in feature coords (grid is convex in poly pts)
    float sxn = (float)W / 1344.0f, syn = (float)H / 800.0f;
    int px0 = min(max((int)floorf(minx * sxn - 0.5f), 0), W - 1);
    int px1 = min(max((int)floorf(maxx * sxn - 0.5f) + 1, 0), W - 1);
    int py0 = min(max((int)floorf(miny * syn - 0.5f), 0), H - 1);
    int py1 = min(max((int)floorf(maxy * syn - 0.5f) + 1, 0), H - 1);
    const int PW = px1 - px0 + 1;
    const int PH = py1 - py0 + 1;
    const int npatch = PH * PW;             // exact stride, no padding
    const bool staged = (PW <= 256) && (npatch <= PMAX);  // uniform per block

    const int pxo = staged ? px0 : 0;
    const int pyo = staged ? py0 : 0;
    const int PWe = staged ? PW  : W;       // !staged -> offsets are global

    // ---- geometry for this thread's 4 consecutive positions ----
    // thread t: channel slot csub = t>>(lwp+1), position group pg
    const int pg   = tid & ((npos >> 2) - 1);
    const int csub = tid >> (lwp + 1);      // pid0: 0..3, pid1: 0..1
    const int npass = pidk ? 2 : 1;         // channels per round / slots

    int   off[4][4];
    float wt [4][4];
#pragma unroll
    for (int k = 0; k < 4; ++k)
        make_geo(pts, 4 * pg + k, lwp, W, H, pxo, pyo, PWe,
                 off[k][0], off[k][1], off[k][2], off[k][3],
                 wt[k][0],  wt[k][1],  wt[k][2],  wt[k][3]);

    if (staged) {
        for (int rnd = 0; rnd < CCHUNK / NSTG; ++rnd) {
            // ---- cooperative coalesced staging of NSTG channel patches ----
            const float* sb = featimg + (size_t)(c0 + rnd * NSTG) * HW
                              + (size_t)py0 * W + px0;
            for (int r = 0; r < PH; r += 2) {
                if (tid < PW) {
                    const float* sA = sb + r * W + tid;
                    float a0 = sA[0], a1 = sA[HW], a2 = sA[2 * HW], a3 = sA[3 * HW];
                    const bool r1 = (r + 1 < PH);
                    const float* sB = sA + W;
                    float b0 = 0, b1 = 0, b2 = 0, b3 = 0;
                    if (r1) { b0 = sB[0]; b1 = sB[HW]; b2 = sB[2 * HW]; b3 = sB[3 * HW]; }
                    int d = r * PW + tid;
                    patch[0][d] = a0; patch[1][d] = a1;
                    patch[2][d] = a2; patch[3][d] = a3;
                    if (r1) {
                        int d2 = d + PW;
                        patch[0][d2] = b0; patch[1][d2] = b1;
                        patch[2][d2] = b2; patch[3][d2] = b3;
                    }
                }
            }
            __syncthreads();

            // ---- compute: each thread -> 4 positions of one channel ----
            for (int cc = 0; cc < npass; ++cc) {
                const int slot = (cc << 1) + csub;      // pid0: csub; pid1: 2cc+csub
                const float* pk = patch[slot];
                f32x4 res;
#pragma unroll
                for (int k = 0; k < 4; ++k)
                    res[k] = wt[k][0] * pk[off[k][0]] + wt[k][1] * pk[off[k][1]]
                           + wt[k][2] * pk[off[k][2]] + wt[k][3] * pk[off[k][3]];
                const int ch = c0 + (rnd << 2) + slot;
                *reinterpret_cast<f32x4*>(outb + (size_t)ch * npos + (pg << 2)) = res;
            }
            __syncthreads();
        }
    } else {
        // ---- fallback: direct global gather (offsets are global here) ----
        for (int rnd = 0; rnd < CCHUNK / NSTG; ++rnd) {
            for (int cc = 0; cc < npass; ++cc) {
                const int slot = (cc << 1) + csub;
                const int ch = c0 + (rnd << 2) + slot;
                const float* fc = featimg + (size_t)ch * HW;
                f32x4 res;
#pragma unroll
                for (int k = 0; k < 4; ++k)
                    res[k] = wt[k][0] * fc[off[k][0]] + wt[k][1] * fc[off[k][1]]
                           + wt[k][2] * fc[off[k][2]] + wt[k][3] * fc[off[k][3]];
                *reinterpret_cast<f32x4*>(outb + (size_t)ch * npos + (pg << 2)) = res;
            }
        }
    }
}

extern "C" void kernel_launch(void* const* d_in, const int* in_sizes, int n_in,
                              void* d_out, int out_size, void* d_ws, size_t ws_size,
                              hipStream_t stream) {
    const float* f0    = (const float*)d_in[0];
    const float* f1    = (const float*)d_in[1];
    const float* f2    = (const float*)d_in[2];
    const float* f3    = (const float*)d_in[3];
    const float* polys = (const float*)d_in[4];
    const int*   ids   = (const int*)d_in[5];
    const int*   lens  = (const int*)d_in[6];
    float* out = (float*)d_out;

    dim3 grid(NCH / CCHUNK, NBOX, 2);   // (8, 256, 2)
    poly_pool_kernel<<<grid, 256, 0, stream>>>(f0, f1, f2, f3, polys, ids, lens, out);
}

// Round 5
// 370.607 us; speedup vs baseline: 1.0712x; 1.0712x over previous
//
#include <hip/hip_runtime.h>

// PolyPoolerTextLenSensitive — MI355X (gfx950)
//
// R4: max-TLP, zero-synchronization structure.
// R0-R3 post-mortem: three gather strategies all ~105-127 µs with every
// pipe <35% busy -> latency/imbalance-bound, not throughput-bound.
//  - merged zero-fill: every block is a real block (grid 16x256); it
//    zero-fills the other pooler's slab for its channels AND computes its
//    own. No empty blocks, uniform store volume.
//  - no LDS staging, no __syncthreads in the hot path: direct global
//    gathers (R1/R2 showed staged vs direct ~= 10%), latency hidden by TLP.
//  - dwordx4 nontemporal stores (4 consecutive positions per thread).
//  - launch_bounds(256,4): <=128 VGPR, 4 blocks/CU resident, 16 queued.

#define NBOX 256
#define NCH  256
#define CCHUNK 16
#define OUT0_ELEMS ((size_t)NBOX * NCH * 8 * 32)

typedef float f32x4 __attribute__((ext_vector_type(4)));

// Bilinear geometry for one grid position: global tap offsets + weights.
__device__ __forceinline__ void make_geo(
    const float* __restrict__ pts, int pos, int lwp, int W, int H,
    int* __restrict__ off, float* __restrict__ wt)
{
    const int wp = 1 << lwp;
    const int i  = pos >> lwp;
    const int j  = pos & (wp - 1);

    // boundary interp parameter (n-1 = 6 segments); /wp is pow2-exact
    float u  = ((j + 0.5f) / (float)wp) * 6.0f;
    int   i0 = (int)floorf(u);
    i0 = min(max(i0, 0), 5);
    float f = u - (float)i0;

    const float inx = 1.0f / 1344.0f, iny = 1.0f / 800.0f;
    // top points: polys[b, i0], polys[b, i0+1] normalized by (1344, 800)
    float txa = pts[2 * i0]     * inx, tya = pts[2 * i0 + 1] * iny;
    float txb = pts[2 * i0 + 2] * inx, tyb = pts[2 * i0 + 3] * iny;
    // bottom points (reversed): pn[7+m] = polys[b, 13-m]
    int ka = 13 - i0, kb = 12 - i0;
    float bxa = pts[2 * ka] * inx, bya = pts[2 * ka + 1] * iny;
    float bxb = pts[2 * kb] * inx, byb = pts[2 * kb + 1] * iny;

    float topx = txa * (1.0f - f) + txb * f;
    float topy = tya * (1.0f - f) + tyb * f;
    float botx = bxa * (1.0f - f) + bxb * f;
    float boty = bya * (1.0f - f) + byb * f;

    float v  = (i + 0.5f) / 8.0f;
    float gx = topx * (1.0f - v) + botx * v;
    float gy = topy * (1.0f - v) + boty * v;

    float x = gx * (float)W - 0.5f;
    float y = gy * (float)H - 0.5f;
    float x0f = floorf(x), y0f = floorf(y);
    float fx = x - x0f,   fy = y - y0f;
    int x0 = (int)x0f, y0 = (int)y0f;
    int x1 = x0 + 1,   y1 = y0 + 1;

    int x0c = min(max(x0, 0), W - 1), x1c = min(max(x1, 0), W - 1);
    int y0c = min(max(y0, 0), H - 1), y1c = min(max(y1, 0), H - 1);
    float m00 = (x0 >= 0 && x0 < W && y0 >= 0 && y0 < H) ? 1.0f : 0.0f;
    float m10 = (x1 >= 0 && x1 < W && y0 >= 0 && y0 < H) ? 1.0f : 0.0f;
    float m01 = (x0 >= 0 && x0 < W && y1 >= 0 && y1 < H) ? 1.0f : 0.0f;
    float m11 = (x1 >= 0 && x1 < W && y1 >= 0 && y1 < H) ? 1.0f : 0.0f;

    off[0] = y0c * W + x0c;  off[1] = y0c * W + x1c;
    off[2] = y1c * W + x0c;  off[3] = y1c * W + x1c;
    wt[0] = (1.0f - fx) * (1.0f - fy) * m00;
    wt[1] = fx * (1.0f - fy) * m10;
    wt[2] = (1.0f - fx) * fy * m01;
    wt[3] = fx * fy * m11;
}

// Real-output compute for one pooler size. Each thread: 4 consecutive
// positions of one channel slot -> one dwordx4 nt store per round.
template<int LWP>
__device__ __forceinline__ void pool_real(
    const float* __restrict__ featimg, int HW, int W, int H,
    const float* __restrict__ pts, float* __restrict__ outR,
    int c0, int tid)
{
    constexpr int NPOS   = 8 << LWP;          // 256 or 512
    constexpr int GROUPS = NPOS / 4;          // 64 or 128
    constexpr int SLOTS  = 256 / GROUPS;      // 4 or 2
    constexpr int ROUNDS = CCHUNK / SLOTS;    // 4 or 8
    const int pg   = tid & (GROUPS - 1);
    const int csub = tid / GROUPS;

    int   off[4][4];
    float wt [4][4];
#pragma unroll
    for (int k = 0; k < 4; ++k)
        make_geo(pts, 4 * pg + k, LWP, W, H, off[k], wt[k]);

#pragma unroll 2
    for (int r = 0; r < ROUNDS; ++r) {
        const int ch = c0 + r * SLOTS + csub;
        const float* fc = featimg + (size_t)ch * HW;
        float t[4][4];
#pragma unroll
        for (int k = 0; k < 4; ++k)
#pragma unroll
            for (int j = 0; j < 4; ++j)
                t[k][j] = fc[off[k][j]];
        f32x4 res;
#pragma unroll
        for (int k = 0; k < 4; ++k)
            res[k] = wt[k][0] * t[k][0] + wt[k][1] * t[k][1]
                   + wt[k][2] * t[k][2] + wt[k][3] * t[k][3];
        __builtin_nontemporal_store(res,
            reinterpret_cast<f32x4*>(outR + (size_t)ch * NPOS + 4 * pg));
    }
}

__global__ __launch_bounds__(256, 4) void poly_pool_kernel(
    const float* __restrict__ f0, const float* __restrict__ f1,
    const float* __restrict__ f2, const float* __restrict__ f3,
    const float* __restrict__ polys, const int* __restrict__ img_ids,
    const int* __restrict__ lens, float* __restrict__ out)
{
    const int b   = blockIdx.y;
    const int c0  = blockIdx.x * CCHUNK;
    const int tid = threadIdx.x;

    __shared__ float pts[28];               // polys[b] : 14 points x 2
    if (tid < 28) pts[tid] = polys[b * 28 + tid];
    __syncthreads();

    // pooler routing: pooler_id = (lens > 8)
    const int pid = (lens[b] > 8) ? 1 : 0;

    // ---- zero-fill the OTHER pooler's slab for these channels ----
    {
        const int nposZ = pid ? 256 : 512;
        float* outZ = out + (pid ? (size_t)0 : OUT0_ELEMS)
                    + (size_t)b * NCH * nposZ + (size_t)c0 * nposZ;
        f32x4 z = (f32x4)(0.0f);
        f32x4* p = reinterpret_cast<f32x4*>(outZ);
        const int total4 = (CCHUNK * nposZ) >> 2;   // 1024 or 2048
        for (int k = tid; k < total4; k += 256)
            __builtin_nontemporal_store(z, p + k);
    }

    // ---- level selection: s = sqrt(dx*dy) over raw points ----
    float minx = pts[0], maxx = pts[0], miny = pts[1], maxy = pts[1];
#pragma unroll
    for (int k = 1; k < 14; ++k) {
        float x = pts[2 * k], y = pts[2 * k + 1];
        minx = fminf(minx, x); maxx = fmaxf(maxx, x);
        miny = fminf(miny, y); maxy = fmaxf(maxy, y);
    }
    float s = sqrtf((maxx - minx) * (maxy - miny));
    int lvl = (int)floorf(4.0f + log2f(s / 224.0f + 1e-6f));
    lvl = min(max(lvl, 2), 5) - 2;

    const float* feat; int H, W;
    switch (lvl) {
        case 0:  feat = f0; H = 200; W = 336; break;
        case 1:  feat = f1; H = 100; W = 168; break;
        case 2:  feat = f2; H = 50;  W = 84;  break;
        default: feat = f3; H = 25;  W = 42;  break;
    }
    const int HW = H * W;
    const float* featimg = feat + (size_t)img_ids[b] * NCH * HW;

    // ---- real output ----
    if (pid == 0) {
        float* outR = out + (size_t)b * NCH * 256;
        pool_real<5>(featimg, HW, W, H, pts, outR, c0, tid);
    } else {
        float* outR = out + OUT0_ELEMS + (size_t)b * NCH * 512;
        pool_real<6>(featimg, HW, W, H, pts, outR, c0, tid);
    }
}

extern "C" void kernel_launch(void* const* d_in, const int* in_sizes, int n_in,
                              void* d_out, int out_size, void* d_ws, size_t ws_size,
                              hipStream_t stream) {
    const float* f0    = (const float*)d_in[0];
    const float* f1    = (const float*)d_in[1];
    const float* f2    = (const float*)d_in[2];
    const float* f3    = (const float*)d_in[3];
    const float* polys = (const float*)d_in[4];
    const int*   ids   = (const int*)d_in[5];
    const int*   lens  = (const int*)d_in[6];
    float* out = (float*)d_out;

    dim3 grid(NCH / CCHUNK, NBOX);      // (16, 256) = 4096 uniform blocks
    poly_pool_kernel<<<grid, 256, 0, stream>>>(f0, f1, f2, f3, polys, ids, lens, out);
}